// Round 7
// baseline (985.792 us; speedup 1.0000x reference)
//
#include <hip/hip_runtime.h>

// Problem constants (fixed by reference)
#define NE 8
#define TT 2048            // tokens per expert
#define KD 2048            // INPUT_SIZE  (K)
#define ND 8192            // OUTPUT_SIZE (N)
#define MT (NE * TT)       // 16384 total rows
#define NW ((size_t)NE * ND * KD)   // 134217728 weight elems
#define NX ((size_t)MT * KD)        // 33554432 input elems

typedef _Float16 f16;
typedef _Float16 f16x4 __attribute__((ext_vector_type(4)));
typedef _Float16 f16x8 __attribute__((ext_vector_type(8)));
typedef float    f32x4  __attribute__((ext_vector_type(4)));
typedef float    f32x16 __attribute__((ext_vector_type(16)));

// ---------------- K1: partial abs-sum (f64, deterministic) ----------------
__global__ void k_abs_partial(const float* __restrict__ w, double* __restrict__ part) {
    __shared__ double sred[256];
    const size_t n4 = NW / 4;
    const size_t stride = (size_t)gridDim.x * blockDim.x;
    double acc = 0.0;
    for (size_t i = (size_t)blockIdx.x * blockDim.x + threadIdx.x; i < n4; i += stride) {
        float4 v = ((const float4*)w)[i];
        acc += (double)fabsf(v.x) + (double)fabsf(v.y) + (double)fabsf(v.z) + (double)fabsf(v.w);
    }
    sred[threadIdx.x] = acc;
    __syncthreads();
    for (int s = 128; s > 0; s >>= 1) {
        if ((int)threadIdx.x < s) sred[threadIdx.x] += sred[threadIdx.x + s];
        __syncthreads();
    }
    if (threadIdx.x == 0) part[blockIdx.x] = sred[0];
}

// ---------------- K2: finalize scale ----------------
__global__ void k_finalize(const double* __restrict__ part, double* __restrict__ sc) {
    __shared__ double sred[256];
    double a = 0.0;
    for (int i = threadIdx.x; i < 2048; i += 256) a += part[i];
    sred[threadIdx.x] = a;
    __syncthreads();
    for (int s = 128; s > 0; s >>= 1) {
        if ((int)threadIdx.x < s) sred[threadIdx.x] += sred[threadIdx.x + s];
        __syncthreads();
    }
    if (threadIdx.x == 0) {
        double mean = sred[0] / (double)NW;
        double denom = mean > 1e-5 ? mean : 1e-5;
        sc[0] = 1.0 / denom;   // scale
        sc[1] = denom;         // 1/scale (output multiplier)
    }
}

// ---------------- K3: quantize w -> ternary f16 ----------------
__global__ void k_quant(const float* __restrict__ w, const double* __restrict__ sc,
                        f16* __restrict__ q) {
    const double scale = sc[0];
    const size_t n4 = NW / 4;
    const size_t stride = (size_t)gridDim.x * blockDim.x;
    for (size_t i = (size_t)blockIdx.x * blockDim.x + threadIdx.x; i < n4; i += stride) {
        float4 v = ((const float4*)w)[i];
        f16x4 o;
        o[0] = (f16)(float)fmin(fmax(rint((double)v.x * scale), -1.0), 1.0);
        o[1] = (f16)(float)fmin(fmax(rint((double)v.y * scale), -1.0), 1.0);
        o[2] = (f16)(float)fmin(fmax(rint((double)v.z * scale), -1.0), 1.0);
        o[3] = (f16)(float)fmin(fmax(rint((double)v.w * scale), -1.0), 1.0);
        ((f16x4*)q)[i] = o;
    }
}

// ---------------- K4: x f32 -> f16 ----------------
__global__ void k_xconv(const float* __restrict__ x, f16* __restrict__ xh) {
    const size_t n4 = NX / 4;
    const size_t stride = (size_t)gridDim.x * blockDim.x;
    for (size_t i = (size_t)blockIdx.x * blockDim.x + threadIdx.x; i < n4; i += stride) {
        float4 v = ((const float4*)x)[i];
        f16x4 o;
        o[0] = (f16)v.x; o[1] = (f16)v.y; o[2] = (f16)v.z; o[3] = (f16)v.w;
        ((f16x4*)xh)[i] = o;
    }
}

// ---------------- K5: grouped GEMM, 256x256x64, 32x32x16 MFMA -------------
// 8 waves (2M x 4N), per-wave 128x64 = 4x2 frags of 32x32, acc = 8 x f32x16.
// LDS: 2 bufs x [Ak0 | Ak1 | Bk0 | Bk1] x 16 KiB = 128 KiB (region = 256
// rows x 64 B = one 32-k half). 2 phases per K-tile:
//   phase(kh) = { 12 ds_read_b128 (base+imm) | stage A-half + B-half of next
//     tile (4 gloads) | s_barrier | lgkmcnt(0)+sched_barrier | setprio(1)
//     16 MFMA setprio(0) | vmcnt(4) | s_barrier }
// vmcnt(4): 8 staging loads outstanding at each phase end; waiting to 4 lands
// the half needed next phase. Barriers are RAW inline-asm s_barrier so the
// compiler cannot attach an implicit vmcnt(0) drain (counted-vmcnt killer).
// Swizzle: 64-B rows, slot s = ks*2+(lane>>5), phys = s ^ (row&3); lanes
// 0-31 / 32-63 fill complementary bank halves -> conflict-free; lane-constant
// per (buf,ks) -> reads are base VGPR + compile-time imm (<= 22528).
// global_load_lds imm stays 0 ALWAYS (nonzero shifts global AND LDS: r4 NaN).
#define NTK 32   // KD / 64

__device__ __forceinline__ void gload16(const void* g, void* l) {
    __builtin_amdgcn_global_load_lds(
        (const __attribute__((address_space(1))) unsigned int*)g,
        (__attribute__((address_space(3))) unsigned int*)l, 16, 0, 0);
}

#define BARR() asm volatile("s_barrier" ::: "memory")
#define LGKM0() do { asm volatile("s_waitcnt lgkmcnt(0)" ::: "memory"); \
                     __builtin_amdgcn_sched_barrier(0); } while (0)
#define VM(N) asm volatile("s_waitcnt vmcnt(" #N ")" ::: "memory")

// 12 fragment reads for one kh half: A (4m x 2ks) + B (2n x 2ks)
#define RD_PH(A0, A1, B0, B1, KH) do { \
  _Pragma("unroll") for (int m_ = 0; m_ < 4; ++m_) { \
    af[m_][0] = *(const f16x8*)((A0) + ((KH) * 16384 + m_ * 2048)); \
    af[m_][1] = *(const f16x8*)((A1) + ((KH) * 16384 + m_ * 2048)); } \
  _Pragma("unroll") for (int n_ = 0; n_ < 2; ++n_) { \
    bf[n_][0] = *(const f16x8*)((B0) + ((KH) * 16384 + n_ * 2048)); \
    bf[n_][1] = *(const f16x8*)((B1) + ((KH) * 16384 + n_ * 2048)); } \
} while (0)

// stage one 16-KiB half (2 gloads), advance that matrix's pointers +64 B
#define STG_A(SB, KH) do { \
    gload16(gA0, dst0 + (SB) + (KH) * 16384); \
    gload16(gA1, dst0 + (SB) + (KH) * 16384 + 1024); \
    gA0 += 64; gA1 += 64; \
    asm volatile("" : "+v"(gA0), "+v"(gA1)); } while (0)
#define STG_B(SB, KH) do { \
    gload16(gB0, dst0 + (SB) + 32768 + (KH) * 16384); \
    gload16(gB1, dst0 + (SB) + 32768 + (KH) * 16384 + 1024); \
    gB0 += 64; gB1 += 64; \
    asm volatile("" : "+v"(gB0), "+v"(gB1)); } while (0)

#define MM_PH() do { \
  __builtin_amdgcn_s_setprio(1); \
  _Pragma("unroll") for (int m_ = 0; m_ < 4; ++m_) \
    _Pragma("unroll") for (int n_ = 0; n_ < 2; ++n_) { \
      acc[m_][n_] = __builtin_amdgcn_mfma_f32_32x32x16_f16( \
          af[m_][0], bf[n_][0], acc[m_][n_], 0, 0, 0); \
      acc[m_][n_] = __builtin_amdgcn_mfma_f32_32x32x16_f16( \
          af[m_][1], bf[n_][1], acc[m_][n_], 0, 0, 0); } \
  __builtin_amdgcn_s_setprio(0); } while (0)

// one K-tile: 2 phases, reading (A0,A1,B0,B1) bases, staging next into SB
#define TILE_S(A0, A1, B0, B1, SB) do { \
    RD_PH(A0, A1, B0, B1, 0); \
    STG_A(SB, 0); STG_B(SB, 0); \
    BARR(); LGKM0(); MM_PH(); VM(4); BARR(); \
    RD_PH(A0, A1, B0, B1, 1); \
    STG_A(SB, 1); STG_B(SB, 1); \
    BARR(); LGKM0(); MM_PH(); VM(4); BARR(); \
} while (0)

#define TILE_LAST(A0, A1, B0, B1) do { \
    RD_PH(A0, A1, B0, B1, 0); \
    BARR(); LGKM0(); MM_PH(); VM(0); BARR(); \
    RD_PH(A0, A1, B0, B1, 1); \
    LGKM0(); MM_PH(); \
} while (0)

__global__ __launch_bounds__(512, 2)
void k_gemm(const f16* __restrict__ xh, const f16* __restrict__ qh,
            const double* __restrict__ sc, float* __restrict__ out) {
    __shared__ char lds[2 * 65536];

    const int lane = (int)threadIdx.x & 63;
    const int wid  = (int)threadIdx.x >> 6;   // 0..7
    const int wr   = wid >> 2;                 // 0..1  (M strip of 128)
    const int wc   = wid & 3;                  // 0..3  (N strip of 64)
    const int r32  = lane & 31;
    const int sl5  = lane >> 5;                // 0..1

    // XCD-aware swizzle; within an XCD: nt-inner sweep so 32 concurrent
    // blocks share ONE 1-MiB A-panel (L2-resident)
    const int wg = ((int)blockIdx.x & 7) * 256 + ((int)blockIdx.x >> 3);
    const int e  = wg >> 8;
    const int u  = wg & 255;
    const int mt = u >> 5;      // 0..7
    const int nt = u & 31;      // 0..31

    const f16* Ab = xh + ((size_t)e * TT + (size_t)mt * 256) * KD;
    const f16* Bb = qh + ((size_t)e * ND + (size_t)nt * 256) * KD;
    float*     Cb = out + ((size_t)e * TT + (size_t)mt * 256) * ND + (size_t)nt * 256;

    const float sfac = (float)sc[1];
    asm volatile("s_waitcnt vmcnt(0)" ::: "memory");

    // read bases: phys slot = (ks*2 + sl5) ^ (r&3), lane-constant per ks
    const int rb3 = r32 & 3;
    const int xk0 = ((sl5 ^ rb3) << 4);
    const int xk1 = (((sl5 + 2) ^ rb3) << 4);
    const char* aB = (const char*)lds + ((wr * 128 + r32) << 6);
    const char* bB = (const char*)lds + 32768 + ((wc * 64 + r32) << 6);
    const char* a00 = aB + xk0;            // buf0, ks0
    const char* a01 = aB + xk1;            // buf0, ks1
    const char* a10 = a00 + 65536;         // buf1
    const char* a11 = a01 + 65536;
    const char* b00 = bB + xk0;
    const char* b01 = bB + xk1;
    const char* b10 = b00 + 65536;
    const char* b11 = b01 + 65536;

    // staging: 2 x 1-KiB chunks per wave per half, inverse-swizzled source
    const int lslot = (lane & 3) ^ ((lane >> 2) & 3);
    char* dst0 = (char*)lds + wid * 2048;
    const int srow0 = (wid * 2 + 0) * 16 + (lane >> 2);   // 0..255
    const int srow1 = (wid * 2 + 1) * 16 + (lane >> 2);
    const char* gA0 = (const char*)(Ab + (size_t)srow0 * KD + lslot * 8);
    const char* gA1 = (const char*)(Ab + (size_t)srow1 * KD + lslot * 8);
    const char* gB0 = (const char*)(Bb + (size_t)srow0 * KD + lslot * 8);
    const char* gB1 = (const char*)(Bb + (size_t)srow1 * KD + lslot * 8);

    f32x16 acc[4][2];
#pragma unroll
    for (int m = 0; m < 4; ++m)
#pragma unroll
        for (int n = 0; n < 2; ++n)
#pragma unroll
            for (int i = 0; i < 16; ++i) acc[m][n][i] = 0.f;

    f16x8 af[4][2], bf[2][2];

    // prologue: stage tile 0 into buf0 (Ak0,Bk0,Ak1,Bk1), wait k0 halves
    STG_A(0, 0);
    STG_B(0, 0);
    STG_A(0, 1);
    STG_B(0, 1);
    VM(4);
    BARR();

    // tiles 0..29 (2 per iteration), then 30, 31
    for (int t2 = 0; t2 < 15; ++t2) {
        TILE_S(a00, a01, b00, b01, 65536);   // even tile: read buf0, stage buf1
        TILE_S(a10, a11, b10, b11, 0);       // odd tile:  read buf1, stage buf0
    }
    TILE_S(a00, a01, b00, b01, 65536);       // tile 30, stage tile 31
    TILE_LAST(a10, a11, b10, b11);           // tile 31

    // ---- epilogue: scale by 1/scale, f32 store ----
    // C/D 32x32 layout: col = lane&31, row = (reg&3) + 8*(reg>>2) + 4*(lane>>5)
    const int colb = wc * 64 + r32;
#pragma unroll
    for (int m = 0; m < 4; ++m)
#pragma unroll
        for (int n = 0; n < 2; ++n)
#pragma unroll
            for (int i = 0; i < 16; ++i) {
                const int row = wr * 128 + m * 32 + (i & 3) + ((i >> 2) << 3) + (sl5 << 2);
                Cb[(size_t)row * ND + colb + n * 32] = acc[m][n][i] * sfac;
            }
}

// ---------------- fallback (only if ws too small): f32 tiled, on-the-fly quant ----------------
__global__ void k_fallback(const float* __restrict__ x, const float* __restrict__ w,
                           const double* __restrict__ sc, float* __restrict__ out) {
    const int row0 = blockIdx.x * 16;
    const int col0 = blockIdx.y * 16;
    const int e = row0 / TT;
    __shared__ float xs[16][17];
    __shared__ float wq[16][17];
    const double scale = sc[0];
    const float s = (float)sc[1];
    const int tx = threadIdx.x, ty = threadIdx.y;
    const float* wbase = w + ((size_t)e * ND + col0) * KD;
    float acc = 0.f;
    for (int k0 = 0; k0 < KD; k0 += 16) {
        xs[ty][tx] = x[(size_t)(row0 + ty) * KD + k0 + tx];
        const float wv = wbase[(size_t)ty * KD + k0 + tx];
        wq[ty][tx] = (float)fmin(fmax(rint((double)wv * scale), -1.0), 1.0);
        __syncthreads();
#pragma unroll
        for (int kk = 0; kk < 16; ++kk) acc += xs[ty][kk] * wq[tx][kk];
        __syncthreads();
    }
    out[(size_t)(row0 + ty) * ND + col0 + tx] = acc * s;
}

// ---------------- launch ----------------
extern "C" void kernel_launch(void* const* d_in, const int* in_sizes, int n_in,
                              void* d_out, int out_size, void* d_ws, size_t ws_size,
                              hipStream_t stream) {
    const float* x = (const float*)d_in[0];
    const float* w = (const float*)d_in[1];
    float* out = (float*)d_out;

    double* part = (double*)d_ws;                       // 2048 * 8 B
    double* sc   = (double*)((char*)d_ws + 16384);      // [0]=scale, [1]=1/scale

    const size_t need = 65536 + NX * 2 + NW * 2;        // ~320 MiB

    hipLaunchKernelGGL(k_abs_partial, dim3(2048), dim3(256), 0, stream, w, part);
    hipLaunchKernelGGL(k_finalize,   dim3(1),    dim3(256), 0, stream, part, sc);

    if (ws_size >= need) {
        f16* xh = (f16*)((char*)d_ws + 65536);
        f16* qh = (f16*)((char*)d_ws + 65536 + NX * 2);
        hipLaunchKernelGGL(k_quant, dim3(2048), dim3(256), 0, stream, w, sc, qh);
        hipLaunchKernelGGL(k_xconv, dim3(2048), dim3(256), 0, stream, x, xh);
        hipLaunchKernelGGL(k_gemm,  dim3(NE * (TT / 256) * (ND / 256)), dim3(512), 0, stream,
                           xh, qh, sc, out);
    } else {
        dim3 grid(MT / 16, ND / 16);
        hipLaunchKernelGGL(k_fallback, grid, dim3(16, 16), 0, stream, x, w, sc, out);
    }
}

// Round 8
// 923.143 us; speedup vs baseline: 1.0679x; 1.0679x over previous
//
#include <hip/hip_runtime.h>

// Problem constants (fixed by reference)
#define NE 8
#define TT 2048            // tokens per expert
#define KD 2048            // INPUT_SIZE  (K)
#define ND 8192            // OUTPUT_SIZE (N)
#define MT (NE * TT)       // 16384 total rows
#define NW ((size_t)NE * ND * KD)   // 134217728 weight elems
#define NX ((size_t)MT * KD)        // 33554432 input elems

typedef _Float16 f16;
typedef _Float16 f16x4 __attribute__((ext_vector_type(4)));
typedef _Float16 f16x8 __attribute__((ext_vector_type(8)));
typedef float    f32x4 __attribute__((ext_vector_type(4)));

// ---------------- K1: partial abs-sum (f64, deterministic) ----------------
__global__ void k_abs_partial(const float* __restrict__ w, double* __restrict__ part) {
    __shared__ double sred[256];
    const size_t n4 = NW / 4;
    const size_t stride = (size_t)gridDim.x * blockDim.x;
    double acc = 0.0;
    for (size_t i = (size_t)blockIdx.x * blockDim.x + threadIdx.x; i < n4; i += stride) {
        float4 v = ((const float4*)w)[i];
        acc += (double)fabsf(v.x) + (double)fabsf(v.y) + (double)fabsf(v.z) + (double)fabsf(v.w);
    }
    sred[threadIdx.x] = acc;
    __syncthreads();
    for (int s = 128; s > 0; s >>= 1) {
        if ((int)threadIdx.x < s) sred[threadIdx.x] += sred[threadIdx.x + s];
        __syncthreads();
    }
    if (threadIdx.x == 0) part[blockIdx.x] = sred[0];
}

// ---------------- K2: finalize scale ----------------
__global__ void k_finalize(const double* __restrict__ part, double* __restrict__ sc) {
    __shared__ double sred[256];
    double a = 0.0;
    for (int i = threadIdx.x; i < 2048; i += 256) a += part[i];
    sred[threadIdx.x] = a;
    __syncthreads();
    for (int s = 128; s > 0; s >>= 1) {
        if ((int)threadIdx.x < s) sred[threadIdx.x] += sred[threadIdx.x + s];
        __syncthreads();
    }
    if (threadIdx.x == 0) {
        double mean = sred[0] / (double)NW;
        double denom = mean > 1e-5 ? mean : 1e-5;
        sc[0] = 1.0 / denom;   // scale
        sc[1] = denom;         // 1/scale (output multiplier)
    }
}

// ---------------- K3: quantize w -> ternary f16 ----------------
__global__ void k_quant(const float* __restrict__ w, const double* __restrict__ sc,
                        f16* __restrict__ q) {
    const double scale = sc[0];
    const size_t n4 = NW / 4;
    const size_t stride = (size_t)gridDim.x * blockDim.x;
    for (size_t i = (size_t)blockIdx.x * blockDim.x + threadIdx.x; i < n4; i += stride) {
        float4 v = ((const float4*)w)[i];
        f16x4 o;
        o[0] = (f16)(float)fmin(fmax(rint((double)v.x * scale), -1.0), 1.0);
        o[1] = (f16)(float)fmin(fmax(rint((double)v.y * scale), -1.0), 1.0);
        o[2] = (f16)(float)fmin(fmax(rint((double)v.z * scale), -1.0), 1.0);
        o[3] = (f16)(float)fmin(fmax(rint((double)v.w * scale), -1.0), 1.0);
        ((f16x4*)q)[i] = o;
    }
}

// ---------------- K4: x f32 -> f16 ----------------
__global__ void k_xconv(const float* __restrict__ x, f16* __restrict__ xh) {
    const size_t n4 = NX / 4;
    const size_t stride = (size_t)gridDim.x * blockDim.x;
    for (size_t i = (size_t)blockIdx.x * blockDim.x + threadIdx.x; i < n4; i += stride) {
        float4 v = ((const float4*)x)[i];
        f16x4 o;
        o[0] = (f16)v.x; o[1] = (f16)v.y; o[2] = (f16)v.z; o[3] = (f16)v.w;
        ((f16x4*)xh)[i] = o;
    }
}

// ---------------- K5: grouped GEMM, 256x256x64, m201-style 4-phase --------
// 8 waves (2M x 4N), per-wave 128x64, 16x16x32 f16 MFMA (round-6 verified
// layout/swizzle). LDS: 2 bufs x [Ak0|Ak1|Bk0|Bk1] x 16 KiB = 128 KiB.
// Per K-tile: 4 phases, one C-quadrant x K=64 each (16 MFMA), quadrant order
// (mh0,nh0),(mh0,nh1),(mh1,nh1),(mh1,nh0):
//   P1: 12 ds_read (A[mh0] 8 + B[nh0] 4) | stage A-hi(t+1) | bar lgkm0 MFMA bar
//   P2:  4 ds_read (B[nh1])              | stage B-lo(t+1) | bar lgkm0 MFMA bar
//   P3:  8 ds_read (A[mh1])              | stage B-hi(t+1) | bar lgkm0 MFMA bar
//   P4:  0 ds_read                       | stage A-lo(t+2)->READ buf | bar
//        schedbar MFMA | vmcnt(2) | bar
// vmcnt(2) once per tile: 10 loads outstanding -> wait 8 (tile t+1 complete),
// keep t+2's A-lo (just issued) in flight. A-lo(t+2) overwrites the currently
// read buffer AFTER its last ds_read (retired at P3's lgkmcnt(0)) -> safe.
// Halves are M/N-row halves: stage = 2 gloads/wave (chunk wid of lo/hi half
// in Ak0 region + same in Ak1 at global +64 B). gload imm stays 0 ALWAYS.

__device__ __forceinline__ void gload16(const void* g, void* l) {
    __builtin_amdgcn_global_load_lds(
        (const __attribute__((address_space(1))) unsigned int*)g,
        (__attribute__((address_space(3))) unsigned int*)l, 16, 0, 0);
}

#define BARR() asm volatile("s_barrier" ::: "memory")
#define SCHED0() __builtin_amdgcn_sched_barrier(0)
#define LGKM0() do { asm volatile("s_waitcnt lgkmcnt(0)" ::: "memory"); SCHED0(); } while (0)
#define VM(N) asm volatile("s_waitcnt vmcnt(" #N ")" ::: "memory")

// quadrant fragment reads: base VGPR + compile-time imm (max 23552)
#define RD_AQ(AR, MH) { _Pragma("unroll") for (int i_ = 0; i_ < 4; ++i_) { \
    af[i_][0] = *(const f16x8*)((AR) + ((MH) * 4096 + i_ * 1024)); \
    af[i_][1] = *(const f16x8*)((AR) + (16384 + (MH) * 4096 + i_ * 1024)); } }
#define RD_BQ(BR, NH, BF) { _Pragma("unroll") for (int n_ = 0; n_ < 2; ++n_) { \
    BF[n_][0] = *(const f16x8*)((BR) + ((NH) * 2048 + n_ * 1024)); \
    BF[n_][1] = *(const f16x8*)((BR) + (16384 + (NH) * 2048 + n_ * 1024)); } }

// stage one half (2 gloads: Ak0/Bk0 chunk + Ak1/Bk1 chunk at global +64 B)
#define STG_H(PTR, DSTOFF) do { \
    gload16((PTR), dstc + (DSTOFF)); \
    gload16((PTR) + 64, dstc + (DSTOFF) + 16384); } while (0)
#define ADV1(P) do { P += 128; asm volatile("" : "+v"(P)); } while (0)

#define MMQ(MB, NB, BF) do { \
  __builtin_amdgcn_s_setprio(1); \
  _Pragma("unroll") for (int m_ = 0; m_ < 4; ++m_) \
    _Pragma("unroll") for (int n_ = 0; n_ < 2; ++n_) { \
      acc[(MB) + m_][(NB) + n_] = __builtin_amdgcn_mfma_f32_16x16x32_f16( \
          af[m_][0], BF[n_][0], acc[(MB) + m_][(NB) + n_], 0, 0, 0); \
      acc[(MB) + m_][(NB) + n_] = __builtin_amdgcn_mfma_f32_16x16x32_f16( \
          af[m_][1], BF[n_][1], acc[(MB) + m_][(NB) + n_], 0, 0, 0); } \
  __builtin_amdgcn_s_setprio(0); } while (0)

// full K-tile: read (AR,BR), stage tile t+1 into SB, t+2's A-lo into RB
#define TILE(AR, BR, SB, RB) do { \
    RD_AQ(AR, 0); RD_BQ(BR, 0, bf0); \
    STG_H(pAhi, (SB) + 8192); ADV1(pAhi); \
    BARR(); LGKM0(); MMQ(0, 0, bf0); BARR(); \
    RD_BQ(BR, 1, bf1); \
    STG_H(pBlo, (SB) + 32768); ADV1(pBlo); \
    BARR(); LGKM0(); MMQ(0, 2, bf1); BARR(); \
    RD_AQ(AR, 1); \
    STG_H(pBhi, (SB) + 40960); ADV1(pBhi); \
    BARR(); LGKM0(); MMQ(4, 2, bf1); BARR(); \
    STG_H(pAlo, (RB)); ADV1(pAlo); \
    BARR(); SCHED0(); MMQ(4, 0, bf0); VM(2); BARR(); \
} while (0)

#define TILE_30(AR, BR, SB) do { \
    RD_AQ(AR, 0); RD_BQ(BR, 0, bf0); \
    STG_H(pAhi, (SB) + 8192); \
    BARR(); LGKM0(); MMQ(0, 0, bf0); BARR(); \
    RD_BQ(BR, 1, bf1); \
    STG_H(pBlo, (SB) + 32768); \
    BARR(); LGKM0(); MMQ(0, 2, bf1); BARR(); \
    RD_AQ(AR, 1); \
    STG_H(pBhi, (SB) + 40960); \
    BARR(); LGKM0(); MMQ(4, 2, bf1); BARR(); \
    BARR(); SCHED0(); MMQ(4, 0, bf0); VM(0); BARR(); \
} while (0)

#define TILE_31(AR, BR) do { \
    RD_AQ(AR, 0); RD_BQ(BR, 0, bf0); \
    BARR(); LGKM0(); MMQ(0, 0, bf0); BARR(); \
    RD_BQ(BR, 1, bf1); \
    BARR(); LGKM0(); MMQ(0, 2, bf1); BARR(); \
    RD_AQ(AR, 1); \
    BARR(); LGKM0(); MMQ(4, 2, bf1); BARR(); \
    SCHED0(); MMQ(4, 0, bf0); \
} while (0)

__global__ __launch_bounds__(512, 2)
void k_gemm(const f16* __restrict__ xh, const f16* __restrict__ qh,
            const double* __restrict__ sc, float* __restrict__ out) {
    __shared__ char lds[2 * 65536];

    const int lane = (int)threadIdx.x & 63;
    const int wid  = (int)threadIdx.x >> 6;   // 0..7
    const int wr   = wid >> 2;                 // 0..1  (M strip of 128)
    const int wc   = wid & 3;                  // 0..3  (N strip of 64)
    const int li   = lane & 15;
    const int sl   = lane >> 4;                // k-slot 0..3

    // XCD-aware swizzle + round-6 block mapping (FETCH ~0.4 GB proven)
    const int wg = ((int)blockIdx.x & 7) * 256 + ((int)blockIdx.x >> 3);
    const int e  = wg >> 8;
    const int u  = wg & 255;
    const int mt = (u >> 1) & 7;
    const int nt = (((u >> 4) << 1) | (u & 1));

    const f16* Ab = xh + ((size_t)e * TT + (size_t)mt * 256) * KD;
    const f16* Bb = qh + ((size_t)e * ND + (size_t)nt * 256) * KD;
    float*     Cb = out + ((size_t)e * TT + (size_t)mt * 256) * ND + (size_t)nt * 256;

    const float sfac = (float)sc[1];
    asm volatile("s_waitcnt vmcnt(0)" ::: "memory");

    // read bases (round-6 verified swizzle pair)
    const int pA = (sl ^ (lane & 3) ^ ((lane >> 2) & 3)) & 3;
    const char* aR0 = (const char*)lds + ((wr * 128 + li) << 6) + (pA << 4);
    const char* bR0 = (const char*)lds + 32768 + ((wc * 64 + li) << 6) + (pA << 4);
    const char* aR1 = aR0 + 65536;
    const char* bR1 = bR0 + 65536;

    // staging: chunk wid within each half-region; inverse-swizzled source
    const int lslot = (lane & 3) ^ ((lane >> 2) & 3) ^ ((lane >> 4) & 3);
    char* dstc = (char*)lds + wid * 1024;
    const int rowL = wid * 16 + (lane >> 2);        // 0..127
    const int rowH = rowL + 128;                    // 128..255
    const char* pAlo = (const char*)(Ab + (size_t)rowL * KD + lslot * 8);
    const char* pAhi = (const char*)(Ab + (size_t)rowH * KD + lslot * 8);
    const char* pBlo = (const char*)(Bb + (size_t)rowL * KD + lslot * 8);
    const char* pBhi = (const char*)(Bb + (size_t)rowH * KD + lslot * 8);

    f32x4 acc[8][4];
#pragma unroll
    for (int m = 0; m < 8; ++m)
#pragma unroll
        for (int n = 0; n < 4; ++n) acc[m][n] = (f32x4){0.f, 0.f, 0.f, 0.f};

    f16x8 af[4][2], bf0[2][2], bf1[2][2];

    // prologue: tile0 (all 4 halves) into buf0, tile1's A-lo into buf1
    STG_H(pAlo, 0);         ADV1(pAlo);
    STG_H(pAhi, 8192);      ADV1(pAhi);
    STG_H(pBlo, 32768);     ADV1(pBlo);
    STG_H(pBhi, 40960);     ADV1(pBhi);
    STG_H(pAlo, 65536);     ADV1(pAlo);
    VM(2);                  // tile0 complete; tile1 A-lo in flight
    BARR();

    // tiles 0..29
#pragma unroll 1
    for (int t2 = 0; t2 < 15; ++t2) {
        TILE(aR0, bR0, 65536, 0);     // even tile: read buf0
        TILE(aR1, bR1, 0, 65536);     // odd tile:  read buf1
    }
    TILE_30(aR0, bR0, 65536);         // tile 30: stage rest of t31, drain
    TILE_31(aR1, bR1);                // tile 31

    // ---- epilogue: scale by 1/scale, f32 store (round-6 verified) ----
#pragma unroll
    for (int m = 0; m < 8; ++m)
#pragma unroll
        for (int n = 0; n < 4; ++n)
#pragma unroll
            for (int r4 = 0; r4 < 4; ++r4) {
                const int row = wr * 128 + m * 16 + sl * 4 + r4;
                const int col = wc * 64 + n * 16 + li;
                Cb[(size_t)row * ND + col] = acc[m][n][r4] * sfac;
            }
}

// ---------------- fallback (only if ws too small): f32 tiled, on-the-fly quant ----------------
__global__ void k_fallback(const float* __restrict__ x, const float* __restrict__ w,
                           const double* __restrict__ sc, float* __restrict__ out) {
    const int row0 = blockIdx.x * 16;
    const int col0 = blockIdx.y * 16;
    const int e = row0 / TT;
    __shared__ float xs[16][17];
    __shared__ float wq[16][17];
    const double scale = sc[0];
    const float s = (float)sc[1];
    const int tx = threadIdx.x, ty = threadIdx.y;
    const float* wbase = w + ((size_t)e * ND + col0) * KD;
    float acc = 0.f;
    for (int k0 = 0; k0 < KD; k0 += 16) {
        xs[ty][tx] = x[(size_t)(row0 + ty) * KD + k0 + tx];
        const float wv = wbase[(size_t)ty * KD + k0 + tx];
        wq[ty][tx] = (float)fmin(fmax(rint((double)wv * scale), -1.0), 1.0);
        __syncthreads();
#pragma unroll
        for (int kk = 0; kk < 16; ++kk) acc += xs[ty][kk] * wq[tx][kk];
        __syncthreads();
    }
    out[(size_t)(row0 + ty) * ND + col0 + tx] = acc * s;
}

// ---------------- launch ----------------
extern "C" void kernel_launch(void* const* d_in, const int* in_sizes, int n_in,
                              void* d_out, int out_size, void* d_ws, size_t ws_size,
                              hipStream_t stream) {
    const float* x = (const float*)d_in[0];
    const float* w = (const float*)d_in[1];
    float* out = (float*)d_out;

    double* part = (double*)d_ws;                       // 2048 * 8 B
    double* sc   = (double*)((char*)d_ws + 16384);      // [0]=scale, [1]=1/scale

    const size_t need = 65536 + NX * 2 + NW * 2;        // ~320 MiB

    hipLaunchKernelGGL(k_abs_partial, dim3(2048), dim3(256), 0, stream, w, part);
    hipLaunchKernelGGL(k_finalize,   dim3(1),    dim3(256), 0, stream, part, sc);

    if (ws_size >= need) {
        f16* xh = (f16*)((char*)d_ws + 65536);
        f16* qh = (f16*)((char*)d_ws + 65536 + NX * 2);
        hipLaunchKernelGGL(k_quant, dim3(2048), dim3(256), 0, stream, w, sc, qh);
        hipLaunchKernelGGL(k_xconv, dim3(2048), dim3(256), 0, stream, x, xh);
        hipLaunchKernelGGL(k_gemm,  dim3(NE * (TT / 256) * (ND / 256)), dim3(512), 0, stream,
                           xh, qh, sc, out);
    } else {
        dim3 grid(MT / 16, ND / 16);
        hipLaunchKernelGGL(k_fallback, grid, dim3(16, 16), 0, stream, x, w, sc, out);
    }
}